// Round 18
// baseline (147.900 us; speedup 1.0000x reference)
//
#include <hip/hip_runtime.h>

// RecurrentDecoder: B=8192, T=100, I=30, H=100.
// R18: two-tile (X/Y) phase pipeline. 256 blocks x 448 threads (7 waves),
// ONE block per CU, B-tile 32 = 16 X-rows + 16 Y-rows. Per phase: MFMA of one
// tile runs from a PREFETCHED A-fragment (read during the other tile's phase,
// after the barrier that sealed it), acts, h-write, prefetch other tile's af,
// barrier. xq lives in 32 REGISTERS (no xq LDS traffic; MFMA C-init = xq reg).
// Dead col 101 = W_d -> po by MFMA (inline, no po-wave). Register cap 256
// (launch_bounds(448,2)): ~110 VGPR + 64 AGPR wfrag. Merged-rcp packed acts.

#define LOG2E 1.44269504088896340736f

typedef _Float16 f16x8 __attribute__((ext_vector_type(8)));
typedef float    f32x4 __attribute__((ext_vector_type(4)));
typedef float    f32x2 __attribute__((ext_vector_type(2)));

__device__ __forceinline__ float rcp_(float x) { return __builtin_amdgcn_rcpf(x); }
__device__ __forceinline__ float exp2_(float x) { return __builtin_amdgcn_exp2f(x); }

#define KS 136   // f16 k-stride (272 B = 17*16 B; 2-way max on af reads)

__global__ __launch_bounds__(448, 2) void lstm_kernel(
    const float* __restrict__ x, const float* __restrict__ Wih,
    const float* __restrict__ Whh, const float* __restrict__ bih,
    const float* __restrict__ bhh, const float* __restrict__ Wd,
    const float* __restrict__ bd, float* __restrict__ out)
{
    __shared__ __align__(16) char smem[128 * KS * 2];     // Wstg(34816) U outb 2x6400
    __shared__ __align__(16) _Float16 hlds[4][16 * KS];   // 17408 B: X0,X1,Y0,Y1
    // total 52224 B

    _Float16* Wstg  = (_Float16*)smem;
    float*    outbX = (float*)smem;          // [16][100]
    float*    outbY = (float*)smem + 1600;   // [16][100]

    const int tid = threadIdx.x;
    const int w   = tid >> 6;      // wave 0..6 -> units w*16..w*16+15
    const int l   = tid & 63;
    const int g   = l >> 4;        // 0..3 -> C rows 4g..4g+3
    const int c   = l & 15;        // col within tile / A row
    const int b0  = blockIdx.x * 32;
    const int u   = w * 16 + c;    // unit 0..111 (100..111 dead; 101 = W_d col)
    const bool wpo = (u == 101);

    // ---- zero LDS (dead cols/channels; h(-1)=0 for both tiles) ----
    for (int i = tid; i < 128 * KS / 2; i += 448) ((unsigned*)Wstg)[i] = 0u;
    for (int i = tid; i < 4 * 16 * KS / 2; i += 448) ((unsigned*)&hlds[0][0])[i] = 0u;
    __syncthreads();

    // ---- chunked W staging (one gate per chunk), pre-scaled, identity cols.
    //      s=0 chunk also stages W_d (unscaled) into dead col 101. ----
    f16x8 wfrag[4][4];   // [s][ks]
    for (int s = 0; s < 4; ++s) {
        const float sc = (s == 2) ? (-2.0f * LOG2E) : (-LOG2E);
        for (int idx = tid; idx < 10000; idx += 448) {
            int uu = idx / 100, k = idx - uu * 100;
            Wstg[uu * KS + k] = (_Float16)(Whh[(s * 100 + uu) * 100 + k] * sc);
        }
        if (s == 0)
            for (int k = tid; k < 100; k += 448)
                Wstg[101 * KS + k] = (_Float16)Wd[k];
        __syncthreads();
        #pragma unroll
        for (int ks = 0; ks < 4; ++ks)
            wfrag[s][ks] = *(const f16x8*)&Wstg[u * KS + ks * 32 + g * 8];
        __syncthreads();
    }

    // ---- xq for both tiles -> REGISTERS (pre-scaled pre-acts incl. bias) ----
    f32x4 xqX[4], xqY[4];
    #pragma unroll
    for (int s = 0; s < 4; ++s) {
        xqX[s] = (f32x4){0.f, 0.f, 0.f, 0.f};
        xqY[s] = (f32x4){0.f, 0.f, 0.f, 0.f};
    }
    if (u < 100) {
        for (int k = 0; k < 30; ++k) {
            float xvX[4], xvY[4];
            #pragma unroll
            for (int r = 0; r < 4; ++r) {
                xvX[r] = x[(b0 + 4 * g + r) * 30 + k];
                xvY[r] = x[(b0 + 16 + 4 * g + r) * 30 + k];
            }
            #pragma unroll
            for (int s = 0; s < 4; ++s) {
                float wv = Wih[(s * 100 + u) * 30 + k];
                #pragma unroll
                for (int r = 0; r < 4; ++r) {
                    xqX[s][r] += xvX[r] * wv;
                    xqY[s][r] += xvY[r] * wv;
                }
            }
        }
        #pragma unroll
        for (int s = 0; s < 4; ++s) {
            float sc = (s == 2) ? (-2.0f * LOG2E) : (-LOG2E);
            float b  = bih[s * 100 + u] + bhh[s * 100 + u];
            #pragma unroll
            for (int r = 0; r < 4; ++r) {
                xqX[s][r] = (xqX[s][r] + b) * sc;
                xqY[s][r] = (xqY[s][r] + b) * sc;
            }
        }
    }
    const float bdv = bd[0];
    f32x2 cregX[2] = {{0.f, 0.f}, {0.f, 0.f}};
    f32x2 cregY[2] = {{0.f, 0.f}, {0.f, 0.f}};

    const int afb = c * KS + g * 8;   // A-frag base (+ks*32), same for all bufs

    // initial prefetch: X step 0 reads hX0 (zeros)
    f16x8 afp[4];
    #pragma unroll
    for (int ks = 0; ks < 4; ++ks)
        afp[ks] = *(const f16x8*)&hlds[0][afb + ks * 32];
    __syncthreads();

    // One phase: MFMA(afp,wfrag,XQ) -> po -> acts(CREG) -> h->WR -> prefetch PF.
#define PHASE(WR, PF, XQ, CREG, OUTB, TCUR)                                   \
    {                                                                         \
        f32x4 acc[4];                                                         \
        _Pragma("unroll")                                                     \
        for (int s = 0; s < 4; ++s)                                           \
            acc[s] = __builtin_amdgcn_mfma_f32_16x16x32_f16(                  \
                    afp[0], wfrag[s][0], XQ[s], 0, 0, 0);                     \
        _Pragma("unroll")                                                     \
        for (int ks = 1; ks < 4; ++ks)                                        \
            _Pragma("unroll")                                                 \
            for (int s = 0; s < 4; ++s)                                       \
                acc[s] = __builtin_amdgcn_mfma_f32_16x16x32_f16(              \
                        afp[ks], wfrag[s][ks], acc[s], 0, 0, 0);              \
        if ((TCUR) > 0 && wpo) {                                              \
            _Pragma("unroll")                                                 \
            for (int r = 0; r < 4; ++r)                                       \
                OUTB[(4 * g + r) * 100 + (TCUR) - 1] = acc[0][r] + bdv;       \
        }                                                                     \
        _Pragma("unroll")                                                     \
        for (int q = 0; q < 2; ++q) {                                         \
            f32x2 A2 = {exp2_(acc[0][2 * q]), exp2_(acc[0][2 * q + 1])};      \
            f32x2 F2 = {exp2_(acc[1][2 * q]), exp2_(acc[1][2 * q + 1])};      \
            f32x2 G2 = {exp2_(acc[2][2 * q]), exp2_(acc[2][2 * q + 1])};      \
            f32x2 O2 = {exp2_(acc[3][2 * q]), exp2_(acc[3][2 * q + 1])};      \
            f32x2 a1 = A2 + 1.0f;                                             \
            f32x2 f1 = F2 + 1.0f;                                             \
            f32x2 g1 = G2 + 1.0f;                                             \
            f32x2 gm = 1.0f - G2;                                             \
            f32x2 ag = a1 * g1;                                               \
            f32x2 num = CREG[q] * ag + gm * f1;                               \
            f32x2 den = ag * f1;                                              \
            f32x2 rd = {rcp_(den[0]), rcp_(den[1])};                          \
            f32x2 cg = num * rd;                                              \
            CREG[q] = cg;                                                     \
            f32x2 cgk = cg * (-2.0f * LOG2E);                                 \
            f32x2 C2 = {exp2_(cgk[0]), exp2_(cgk[1])};                        \
            f32x2 c2m = 1.0f - C2;                                            \
            f32x2 od = (O2 + 1.0f) * (C2 + 1.0f);                             \
            f32x2 ro = {rcp_(od[0]), rcp_(od[1])};                            \
            f32x2 hv = c2m * ro;                                              \
            (WR)[(4 * g + 2 * q) * KS + u]     = (_Float16)hv[0];             \
            (WR)[(4 * g + 2 * q + 1) * KS + u] = (_Float16)hv[1];             \
        }                                                                     \
        _Pragma("unroll")                                                     \
        for (int ks = 0; ks < 4; ++ks)                                        \
            afp[ks] = *(const f16x8*)&(PF)[afb + ks * 32];                    \
        __syncthreads();                                                      \
    }

    // buffers: hlds[0]=X0 hlds[1]=X1 hlds[2]=Y0 hlds[3]=Y1.
    // step t: tile reads buf[t&1], writes buf[(t&1)^1].
    for (int t2 = 0; t2 < 50; ++t2) {
        const int t0 = 2 * t2, t1 = 2 * t2 + 1;
        PHASE(&hlds[1][0], &hlds[2][0], xqX, cregX, outbX, t0)  // X t0: wr X1, pf Y0
        PHASE(&hlds[3][0], &hlds[1][0], xqY, cregY, outbY, t0)  // Y t0: wr Y1, pf X1
        PHASE(&hlds[0][0], &hlds[3][0], xqX, cregX, outbX, t1)  // X t1: wr X0, pf Y1
        PHASE(&hlds[2][0], &hlds[0][0], xqY, cregY, outbY, t1)  // Y t1: wr Y0, pf X0
    }
#undef PHASE

    // epilogue: po(99) for X (afp = hX0 = h_X(99), prefetched by last phase)
    {
        f32x4 a99 = {0.f, 0.f, 0.f, 0.f};
        #pragma unroll
        for (int ks = 0; ks < 4; ++ks)
            a99 = __builtin_amdgcn_mfma_f32_16x16x32_f16(
                    afp[ks], wfrag[0][ks], a99, 0, 0, 0);
        if (wpo) {
            #pragma unroll
            for (int r = 0; r < 4; ++r)
                outbX[(4 * g + r) * 100 + 99] = a99[r] + bdv;
        }
    }
    // po(99) for Y (h_Y(99) is in hlds[2])
    {
        f32x4 a99 = {0.f, 0.f, 0.f, 0.f};
        #pragma unroll
        for (int ks = 0; ks < 4; ++ks) {
            f16x8 a = *(const f16x8*)&hlds[2][afb + ks * 32];
            a99 = __builtin_amdgcn_mfma_f32_16x16x32_f16(a, wfrag[0][ks], a99, 0, 0, 0);
        }
        if (wpo) {
            #pragma unroll
            for (int r = 0; r < 4; ++r)
                outbY[(4 * g + r) * 100 + 99] = a99[r] + bdv;
        }
    }
    __syncthreads();

    // coalesced write: 32 rows x 100 = 3200 contiguous floats (X rows then Y rows)
    {
        const float* s4 = (const float*)smem;
        for (int i = tid; i < 3200; i += 448)
            out[b0 * 100 + i] = s4[i];
    }
}

extern "C" void kernel_launch(void* const* d_in, const int* in_sizes, int n_in,
                              void* d_out, int out_size, void* d_ws, size_t ws_size,
                              hipStream_t stream) {
    (void)in_sizes; (void)n_in; (void)out_size; (void)d_ws; (void)ws_size;
    const float* x   = (const float*)d_in[0];
    const float* Wih = (const float*)d_in[1];
    const float* Whh = (const float*)d_in[2];
    const float* bih = (const float*)d_in[3];
    const float* bhh = (const float*)d_in[4];
    const float* Wd  = (const float*)d_in[5];
    const float* bd  = (const float*)d_in[6];
    lstm_kernel<<<dim3(256), dim3(448), 0, stream>>>(
        x, Wih, Whh, bih, bhh, Wd, bd, (float*)d_out);
}

// Round 19
// 145.253 us; speedup vs baseline: 1.0182x; 1.0182x over previous
//
#include <hip/hip_runtime.h>

// RecurrentDecoder: B=8192, T=100, I=30, H=100.
// R19 = R17 (best, 138.7us) + xq stored as PACKED F16 in LDS: per-step xq
// reload is 2 ds_read_b128 (was 4), unpacked to f32 by v_cvt in the
// pre-barrier shadow window. Tests the LDS-instruction-issue-bound theory.
// 512 blocks x 448 threads (7 waves), B-tile 16, identity unit cols.
// Dead col 101 = W_d -> col-101 lanes' acc[0] = po after the normal MFMA pass.
// wfrag 64 AGPR + ~64 VGPR -> 2 blocks/CU. ks-outer MFMA, packed-f32
// merged-rcp acts (7 trans/cell), 1 barrier/step, no VMEM in loop.

#define LOG2E 1.44269504088896340736f

typedef _Float16 f16x8 __attribute__((ext_vector_type(8)));
typedef _Float16 f16x2v __attribute__((ext_vector_type(2)));
typedef float    f32x4 __attribute__((ext_vector_type(4)));
typedef float    f32x2 __attribute__((ext_vector_type(2)));
typedef unsigned u32x4 __attribute__((ext_vector_type(4)));

__device__ __forceinline__ float rcp_(float x) { return __builtin_amdgcn_rcpf(x); }
__device__ __forceinline__ float exp2_(float x) { return __builtin_amdgcn_exp2f(x); }

__device__ __forceinline__ unsigned pk_f16(float a, float b) {
    return __builtin_bit_cast(unsigned, __builtin_amdgcn_cvt_pkrtz(a, b));
}
__device__ __forceinline__ float lo_(unsigned v) {
    f16x2v h = __builtin_bit_cast(f16x2v, v); return (float)h[0];
}
__device__ __forceinline__ float hi_(unsigned v) {
    f16x2v h = __builtin_bit_cast(f16x2v, v); return (float)h[1];
}

#define KS 136   // f16 k-stride (272 B = 17*16 B; 2-way max on af reads)

__global__ __launch_bounds__(448, 4) void lstm_kernel(
    const float* __restrict__ x, const float* __restrict__ Wih,
    const float* __restrict__ Whh, const float* __restrict__ bih,
    const float* __restrict__ bhh, const float* __restrict__ Wd,
    const float* __restrict__ bd, float* __restrict__ out)
{
    __shared__ __align__(16) char smem[128 * KS * 2];      // Wstg(34816) U outb(6400)
    __shared__ __align__(16) _Float16 hlds[2][16 * KS];    //  8704 B (dbuf)
    __shared__ __align__(16) unsigned xq_lds[7 * 2 * 64 * 4]; // 14336 B (packed f16)
    // total 57856 B -> 2 blocks/CU

    _Float16* Wstg = (_Float16*)smem;
    float*    outb = (float*)smem;

    const int tid = threadIdx.x;
    const int w   = tid >> 6;      // wave 0..6 -> units w*16..w*16+15
    const int l   = tid & 63;
    const int g   = l >> 4;        // 0..3 -> C rows 4g..4g+3
    const int c   = l & 15;        // col within tile / A row
    const int b0  = blockIdx.x * 16;
    const int u   = w * 16 + c;    // unit 0..111 (100..111 dead; 101 = W_d col)
    const bool wpo = (u == 101);   // po-column owner lanes (one per g)

    // ---- zero LDS (covers dead cols/channels; h(-1)=0) ----
    for (int i = tid; i < 128 * KS / 2; i += 448) ((unsigned*)Wstg)[i] = 0u;
    for (int i = tid; i < 2 * 16 * KS / 2; i += 448) ((unsigned*)&hlds[0][0])[i] = 0u;
    __syncthreads();

    // ---- chunked W staging (one gate per chunk), pre-scaled, identity cols.
    //      s=0 chunk also stages W_d (unscaled) into dead col 101. ----
    f16x8 wfrag[4][4];   // [s][ks]
    for (int s = 0; s < 4; ++s) {
        const float sc = (s == 2) ? (-2.0f * LOG2E) : (-LOG2E);
        for (int idx = tid; idx < 10000; idx += 448) {
            int uu = idx / 100, k = idx - uu * 100;
            Wstg[uu * KS + k] = (_Float16)(Whh[(s * 100 + uu) * 100 + k] * sc);
        }
        if (s == 0)
            for (int k = tid; k < 100; k += 448)
                Wstg[101 * KS + k] = (_Float16)Wd[k];
        __syncthreads();
        #pragma unroll
        for (int ks = 0; ks < 4; ++ks)
            wfrag[s][ks] = *(const f16x8*)&Wstg[u * KS + ks * 32 + g * 8];
        __syncthreads();
    }
    // (col-101 lane: wfrag[0] = W_d column; wfrag[1..3] = zero columns ->
    //  garbage-but-finite acts; its h lands in channel 101 whose W K-rows are
    //  zero, so nothing propagates.)

    // ---- xq -> LDS as packed f16: pair p holds gates s=2p,2p+1 (16 B/lane) ----
    {
        float xq[4][4];
        #pragma unroll
        for (int s = 0; s < 4; ++s)
            #pragma unroll
            for (int r = 0; r < 4; ++r) xq[s][r] = 0.0f;
        if (u < 100) {
            for (int k = 0; k < 30; ++k) {
                float xv[4];
                #pragma unroll
                for (int r = 0; r < 4; ++r) xv[r] = x[(b0 + 4 * g + r) * 30 + k];
                #pragma unroll
                for (int s = 0; s < 4; ++s) {
                    float wv = Wih[(s * 100 + u) * 30 + k];
                    #pragma unroll
                    for (int r = 0; r < 4; ++r) xq[s][r] += xv[r] * wv;
                }
            }
            #pragma unroll
            for (int s = 0; s < 4; ++s) {
                float sc = (s == 2) ? (-2.0f * LOG2E) : (-LOG2E);
                float b  = bih[s * 100 + u] + bhh[s * 100 + u];
                #pragma unroll
                for (int r = 0; r < 4; ++r) xq[s][r] = (xq[s][r] + b) * sc;
            }
        }
        #pragma unroll
        for (int p = 0; p < 2; ++p) {
            u32x4 vv = {pk_f16(xq[2 * p][0],     xq[2 * p][1]),
                        pk_f16(xq[2 * p][2],     xq[2 * p][3]),
                        pk_f16(xq[2 * p + 1][0], xq[2 * p + 1][1]),
                        pk_f16(xq[2 * p + 1][2], xq[2 * p + 1][3])};
            *(u32x4*)&xq_lds[((w * 2 + p) * 64 + l) * 4] = vv;
        }
    }
    const float bdv = bd[0];
    f32x2 creg2[2] = {{0.f, 0.f}, {0.f, 0.f}};
    __syncthreads();

    const int afb = c * KS + g * 8;                 // A-frag base (+ks*32)
    const int xqb = (w * 2 * 64 + l) * 4;           // xq base; pair stride 256 words

    // acc persists across steps: next step's C-init (xq), refilled pre-barrier.
    f32x4 acc[4];
    {
        u32x4 ra = *(const u32x4*)&xq_lds[xqb];
        u32x4 rb = *(const u32x4*)&xq_lds[xqb + 256];
        acc[0] = (f32x4){lo_(ra[0]), hi_(ra[0]), lo_(ra[1]), hi_(ra[1])};
        acc[1] = (f32x4){lo_(ra[2]), hi_(ra[2]), lo_(ra[3]), hi_(ra[3])};
        acc[2] = (f32x4){lo_(rb[0]), hi_(rb[0]), lo_(rb[1]), hi_(rb[1])};
        acc[3] = (f32x4){lo_(rb[2]), hi_(rb[2]), lo_(rb[3]), hi_(rb[3])};
    }
    __syncthreads();

    // one LSTM step; P = buffer parity (compile-time), TCUR = step index
#define STEP(P, TCUR)                                                         \
    {                                                                         \
        const _Float16* hr = &hlds[(P)][0];                                   \
        _Float16*       hw = &hlds[(P) ^ 1][0];                               \
        f16x8 af[4];                                                          \
        _Pragma("unroll")                                                     \
        for (int ks = 0; ks < 4; ++ks)                                        \
            af[ks] = *(const f16x8*)&hr[afb + ks * 32];                       \
        _Pragma("unroll")                                                     \
        for (int ks = 0; ks < 4; ++ks)                                        \
            _Pragma("unroll")                                                 \
            for (int s = 0; s < 4; ++s)                                       \
                acc[s] = __builtin_amdgcn_mfma_f32_16x16x32_f16(              \
                        af[ks], wfrag[s][ks], acc[s], 0, 0, 0);               \
        /* po(t-1) = h(t-1)@W_d sits in the col-101 lanes' acc[0] */          \
        if ((TCUR) > 0 && wpo) {                                              \
            _Pragma("unroll")                                                 \
            for (int r = 0; r < 4; ++r)                                       \
                outb[(4 * g + r) * 100 + (TCUR) - 1] = acc[0][r] + bdv;       \
        }                                                                     \
        /* packed-f32 activations on row-pairs q */                           \
        _Pragma("unroll")                                                     \
        for (int q = 0; q < 2; ++q) {                                         \
            f32x2 A2 = {exp2_(acc[0][2 * q]), exp2_(acc[0][2 * q + 1])};      \
            f32x2 F2 = {exp2_(acc[1][2 * q]), exp2_(acc[1][2 * q + 1])};      \
            f32x2 G2 = {exp2_(acc[2][2 * q]), exp2_(acc[2][2 * q + 1])};      \
            f32x2 O2 = {exp2_(acc[3][2 * q]), exp2_(acc[3][2 * q + 1])};      \
            f32x2 a1 = A2 + 1.0f;                                             \
            f32x2 f1 = F2 + 1.0f;                                             \
            f32x2 g1 = G2 + 1.0f;                                             \
            f32x2 gm = 1.0f - G2;                                             \
            f32x2 ag = a1 * g1;                                               \
            f32x2 num = creg2[q] * ag + gm * f1;                              \
            f32x2 den = ag * f1;                                              \
            f32x2 rd = {rcp_(den[0]), rcp_(den[1])};                          \
            f32x2 cg = num * rd;                                              \
            creg2[q] = cg;                                                    \
            f32x2 cgk = cg * (-2.0f * LOG2E);                                 \
            f32x2 C2 = {exp2_(cgk[0]), exp2_(cgk[1])};                        \
            f32x2 c2m = 1.0f - C2;                                            \
            f32x2 od = (O2 + 1.0f) * (C2 + 1.0f);                             \
            f32x2 ro = {rcp_(od[0]), rcp_(od[1])};                            \
            f32x2 hv = c2m * ro;                                              \
            hw[(4 * g + 2 * q) * KS + u]     = (_Float16)hv[0];               \
            hw[(4 * g + 2 * q + 1) * KS + u] = (_Float16)hv[1];               \
        }                                                                     \
        /* refill next step's C-init (2 ds_read + cvt) in the shadow */       \
        {                                                                     \
            u32x4 ra = *(const u32x4*)&xq_lds[xqb];                           \
            u32x4 rb = *(const u32x4*)&xq_lds[xqb + 256];                     \
            acc[0] = (f32x4){lo_(ra[0]), hi_(ra[0]), lo_(ra[1]), hi_(ra[1])}; \
            acc[1] = (f32x4){lo_(ra[2]), hi_(ra[2]), lo_(ra[3]), hi_(ra[3])}; \
            acc[2] = (f32x4){lo_(rb[0]), hi_(rb[0]), lo_(rb[1]), hi_(rb[1])}; \
            acc[3] = (f32x4){lo_(rb[2]), hi_(rb[2]), lo_(rb[3]), hi_(rb[3])}; \
        }                                                                     \
        __syncthreads();                                                      \
    }

    for (int t2 = 0; t2 < 50; ++t2) {
        STEP(0, 2 * t2);
        STEP(1, 2 * t2 + 1);
    }
#undef STEP

    // epilogue: po(99) from h(99) (in hlds[0]) via one more s=0 MFMA chain
    {
        f32x4 a99 = {0.f, 0.f, 0.f, 0.f};
        #pragma unroll
        for (int ks = 0; ks < 4; ++ks) {
            f16x8 a = *(const f16x8*)&hlds[0][afb + ks * 32];
            a99 = __builtin_amdgcn_mfma_f32_16x16x32_f16(a, wfrag[0][ks], a99, 0, 0, 0);
        }
        if (wpo) {
            #pragma unroll
            for (int r = 0; r < 4; ++r)
                outb[(4 * g + r) * 100 + 99] = a99[r] + bdv;
        }
    }
    __syncthreads();

    // coalesced vector write of the block's 16x100 outputs
    {
        f32x4*       o4 = (f32x4*)(out + b0 * 100);
        const f32x4* s4 = (const f32x4*)outb;
        for (int i = tid; i < 400; i += 448) o4[i] = s4[i];
    }
}

extern "C" void kernel_launch(void* const* d_in, const int* in_sizes, int n_in,
                              void* d_out, int out_size, void* d_ws, size_t ws_size,
                              hipStream_t stream) {
    (void)in_sizes; (void)n_in; (void)out_size; (void)d_ws; (void)ws_size;
    const float* x   = (const float*)d_in[0];
    const float* Wih = (const float*)d_in[1];
    const float* Whh = (const float*)d_in[2];
    const float* bih = (const float*)d_in[3];
    const float* bhh = (const float*)d_in[4];
    const float* Wd  = (const float*)d_in[5];
    const float* bd  = (const float*)d_in[6];
    lstm_kernel<<<dim3(512), dim3(448), 0, stream>>>(
        x, Wih, Whh, bih, bhh, Wd, bd, (float*)d_out);
}

// Round 20
// 138.809 us; speedup vs baseline: 1.0655x; 1.0464x over previous
//
#include <hip/hip_runtime.h>

// RecurrentDecoder: B=8192, T=100, I=30, H=100.
// R20 = exact revert to R17 (best measured: 138.7 us).
// 512 blocks x 448 threads (7 waves), B-tile 16, identity unit cols.
// Dead col 101 = W_d -> col-101 lanes' acc[0] is the decoder output po after
// the normal MFMA pass (no dedicated po-wave). xq in LDS (f32, swizzled),
// prefetched pre-barrier into the dead acc registers. wfrag 64 AGPR + 64 VGPR
// -> 2 blocks/CU -> 3.5 waves/SIMD. ks-outer MFMA, packed-f32 merged-rcp acts
// (7 trans/cell), 1 barrier/step, no VMEM in loop.
//
// Session evidence (R12-R19): conflicts, DS-instruction count, inter-block
// phase, and occupancy are all non-binding; the step is set by the post-
// barrier critical chain (af ds_read -> MFMA -> trans chain -> h write ->
// barrier) of the per-step all-to-all h exchange. Keep that path minimal.

#define LOG2E 1.44269504088896340736f

typedef _Float16 f16x8 __attribute__((ext_vector_type(8)));
typedef float    f32x4 __attribute__((ext_vector_type(4)));
typedef float    f32x2 __attribute__((ext_vector_type(2)));

__device__ __forceinline__ float rcp_(float x) { return __builtin_amdgcn_rcpf(x); }
__device__ __forceinline__ float exp2_(float x) { return __builtin_amdgcn_exp2f(x); }

#define KS 136     // f16 k-stride (272 B = 17*16 B; 2-way max on af reads)
#define XQR 288    // xq row stride in words (covers swizzled offsets up to 284)

__global__ __launch_bounds__(448, 4) void lstm_kernel(
    const float* __restrict__ x, const float* __restrict__ Wih,
    const float* __restrict__ Whh, const float* __restrict__ bih,
    const float* __restrict__ bhh, const float* __restrict__ Wd,
    const float* __restrict__ bd, float* __restrict__ out)
{
    __shared__ __align__(16) char smem[128 * KS * 2];      // Wstg(34816) U outb(6400)
    __shared__ __align__(16) _Float16 hlds[2][16 * KS];    //  8704 B (dbuf)
    __shared__ __align__(16) float xq_lds[7 * 4 * XQR];    // 32256 B (swizzled)
    // total 75776 B -> 2 blocks/CU

    _Float16* Wstg = (_Float16*)smem;
    float*    outb = (float*)smem;

    const int tid = threadIdx.x;
    const int w   = tid >> 6;      // wave 0..6 -> units w*16..w*16+15
    const int l   = tid & 63;
    const int g   = l >> 4;        // 0..3 -> C rows 4g..4g+3
    const int c   = l & 15;        // col within tile / A row
    const int b0  = blockIdx.x * 16;
    const int u   = w * 16 + c;    // unit 0..111 (100..111 dead; 101 = W_d col)
    const bool wpo = (u == 101);   // po-column owner lanes (one per g)

    // ---- zero LDS (covers dead cols/channels; h(-1)=0) ----
    for (int i = tid; i < 128 * KS / 2; i += 448) ((unsigned*)Wstg)[i] = 0u;
    for (int i = tid; i < 2 * 16 * KS / 2; i += 448) ((unsigned*)&hlds[0][0])[i] = 0u;
    __syncthreads();

    // ---- chunked W staging (one gate per chunk), pre-scaled, identity cols.
    //      s=0 chunk also stages W_d (unscaled) into dead col 101. ----
    f16x8 wfrag[4][4];   // [s][ks]
    for (int s = 0; s < 4; ++s) {
        const float sc = (s == 2) ? (-2.0f * LOG2E) : (-LOG2E);
        for (int idx = tid; idx < 10000; idx += 448) {
            int uu = idx / 100, k = idx - uu * 100;
            Wstg[uu * KS + k] = (_Float16)(Whh[(s * 100 + uu) * 100 + k] * sc);
        }
        if (s == 0)
            for (int k = tid; k < 100; k += 448)
                Wstg[101 * KS + k] = (_Float16)Wd[k];
        __syncthreads();
        #pragma unroll
        for (int ks = 0; ks < 4; ++ks)
            wfrag[s][ks] = *(const f16x8*)&Wstg[u * KS + ks * 32 + g * 8];
        __syncthreads();
    }
    // (col-101 lane: wfrag[0] = W_d column; wfrag[1..3] = zero columns ->
    //  garbage-but-finite acts; its h lands in channel 101 whose W K-rows are
    //  zero, so nothing propagates.)

    // ---- xq -> swizzled LDS (pre-scaled gate pre-acts incl. bias) ----
    const int xqsw = l * 4 + ((l >> 3) << 2);
    {
        float xq[4][4];
        #pragma unroll
        for (int s = 0; s < 4; ++s)
            #pragma unroll
            for (int r = 0; r < 4; ++r) xq[s][r] = 0.0f;
        if (u < 100) {
            for (int k = 0; k < 30; ++k) {
                float xv[4];
                #pragma unroll
                for (int r = 0; r < 4; ++r) xv[r] = x[(b0 + 4 * g + r) * 30 + k];
                #pragma unroll
                for (int s = 0; s < 4; ++s) {
                    float wv = Wih[(s * 100 + u) * 30 + k];
                    #pragma unroll
                    for (int r = 0; r < 4; ++r) xq[s][r] += xv[r] * wv;
                }
            }
            #pragma unroll
            for (int s = 0; s < 4; ++s) {
                float sc = (s == 2) ? (-2.0f * LOG2E) : (-LOG2E);
                float b  = bih[s * 100 + u] + bhh[s * 100 + u];
                #pragma unroll
                for (int r = 0; r < 4; ++r) xq[s][r] = (xq[s][r] + b) * sc;
            }
        }
        #pragma unroll
        for (int s = 0; s < 4; ++s) {
            f32x4 v = {xq[s][0], xq[s][1], xq[s][2], xq[s][3]};
            *(f32x4*)&xq_lds[(w * 4 + s) * XQR + xqsw] = v;
        }
    }
    const float bdv = bd[0];
    f32x2 creg2[2] = {{0.f, 0.f}, {0.f, 0.f}};
    __syncthreads();

    const int afb = c * KS + g * 8;                 // A-frag base (+ks*32)
    const int xqb = w * 4 * XQR + xqsw;             // xq base (+s*XQR)

    // acc persists across steps: holds next step's C-init (xq, prefetched
    // pre-barrier into the dead registers).
    f32x4 acc[4];
    #pragma unroll
    for (int s = 0; s < 4; ++s)
        acc[s] = *(const f32x4*)&xq_lds[xqb + s * XQR];
    __syncthreads();

    // one LSTM step; P = buffer parity (compile-time), TCUR = step index
#define STEP(P, TCUR)                                                         \
    {                                                                         \
        const _Float16* hr = &hlds[(P)][0];                                   \
        _Float16*       hw = &hlds[(P) ^ 1][0];                               \
        f16x8 af[4];                                                          \
        _Pragma("unroll")                                                     \
        for (int ks = 0; ks < 4; ++ks)                                        \
            af[ks] = *(const f16x8*)&hr[afb + ks * 32];                       \
        _Pragma("unroll")                                                     \
        for (int ks = 0; ks < 4; ++ks)                                        \
            _Pragma("unroll")                                                 \
            for (int s = 0; s < 4; ++s)                                       \
                acc[s] = __builtin_amdgcn_mfma_f32_16x16x32_f16(              \
                        af[ks], wfrag[s][ks], acc[s], 0, 0, 0);               \
        /* po(t-1) = h(t-1)@W_d sits in the col-101 lanes' acc[0] */          \
        if ((TCUR) > 0 && wpo) {                                              \
            _Pragma("unroll")                                                 \
            for (int r = 0; r < 4; ++r)                                       \
                outb[(4 * g + r) * 100 + (TCUR) - 1] = acc[0][r] + bdv;       \
        }                                                                     \
        /* packed-f32 activations on row-pairs q */                           \
        _Pragma("unroll")                                                     \
        for (int q = 0; q < 2; ++q) {                                         \
            f32x2 A2 = {exp2_(acc[0][2 * q]), exp2_(acc[0][2 * q + 1])};      \
            f32x2 F2 = {exp2_(acc[1][2 * q]), exp2_(acc[1][2 * q + 1])};      \
            f32x2 G2 = {exp2_(acc[2][2 * q]), exp2_(acc[2][2 * q + 1])};      \
            f32x2 O2 = {exp2_(acc[3][2 * q]), exp2_(acc[3][2 * q + 1])};      \
            f32x2 a1 = A2 + 1.0f;                                             \
            f32x2 f1 = F2 + 1.0f;                                             \
            f32x2 g1 = G2 + 1.0f;                                             \
            f32x2 gm = 1.0f - G2;                                             \
            f32x2 ag = a1 * g1;                                               \
            f32x2 num = creg2[q] * ag + gm * f1;                              \
            f32x2 den = ag * f1;                                              \
            f32x2 rd = {rcp_(den[0]), rcp_(den[1])};                          \
            f32x2 cg = num * rd;                                              \
            creg2[q] = cg;                                                    \
            f32x2 cgk = cg * (-2.0f * LOG2E);                                 \
            f32x2 C2 = {exp2_(cgk[0]), exp2_(cgk[1])};                        \
            f32x2 c2m = 1.0f - C2;                                            \
            f32x2 od = (O2 + 1.0f) * (C2 + 1.0f);                             \
            f32x2 ro = {rcp_(od[0]), rcp_(od[1])};                            \
            f32x2 hv = c2m * ro;                                              \
            hw[(4 * g + 2 * q) * KS + u]     = (_Float16)hv[0];               \
            hw[(4 * g + 2 * q + 1) * KS + u] = (_Float16)hv[1];               \
        }                                                                     \
        /* prefetch next step's C-init while the LDS pipe is idle */          \
        _Pragma("unroll")                                                     \
        for (int s = 0; s < 4; ++s)                                           \
            acc[s] = *(const f32x4*)&xq_lds[xqb + s * XQR];                   \
        __syncthreads();                                                      \
    }

    for (int t2 = 0; t2 < 50; ++t2) {
        STEP(0, 2 * t2);
        STEP(1, 2 * t2 + 1);
    }
#undef STEP

    // epilogue: po(99) from h(99) (in hlds[0]) via one more s=0 MFMA chain
    {
        f32x4 a99 = {0.f, 0.f, 0.f, 0.f};
        #pragma unroll
        for (int ks = 0; ks < 4; ++ks) {
            f16x8 a = *(const f16x8*)&hlds[0][afb + ks * 32];
            a99 = __builtin_amdgcn_mfma_f32_16x16x32_f16(a, wfrag[0][ks], a99, 0, 0, 0);
        }
        if (wpo) {
            #pragma unroll
            for (int r = 0; r < 4; ++r)
                outb[(4 * g + r) * 100 + 99] = a99[r] + bdv;
        }
    }
    __syncthreads();

    // coalesced vector write of the block's 16x100 outputs
    {
        f32x4*       o4 = (f32x4*)(out + b0 * 100);
        const f32x4* s4 = (const f32x4*)outb;
        for (int i = tid; i < 400; i += 448) o4[i] = s4[i];
    }
}

extern "C" void kernel_launch(void* const* d_in, const int* in_sizes, int n_in,
                              void* d_out, int out_size, void* d_ws, size_t ws_size,
                              hipStream_t stream) {
    (void)in_sizes; (void)n_in; (void)out_size; (void)d_ws; (void)ws_size;
    const float* x   = (const float*)d_in[0];
    const float* Wih = (const float*)d_in[1];
    const float* Whh = (const float*)d_in[2];
    const float* bih = (const float*)d_in[3];
    const float* bhh = (const float*)d_in[4];
    const float* Wd  = (const float*)d_in[5];
    const float* bd  = (const float*)d_in[6];
    lstm_kernel<<<dim3(512), dim3(448), 0, stream>>>(
        x, Wih, Whh, bih, bhh, Wd, bd, (float*)d_out);
}